// Round 5
// baseline (194.002 us; speedup 1.0000x reference)
//
#include <hip/hip_runtime.h>
#include <hip/hip_bf16.h>

typedef __attribute__((ext_vector_type(8))) short bf16x8;
typedef __attribute__((ext_vector_type(16))) float f32x16;

static __device__ __forceinline__ uint bf16rne(float f) {
    uint u = __float_as_uint(f);
    return (u + 0x7fffu + ((u >> 16) & 1u)) >> 16;
}

// K1: style_plus1[b][c] = 1 + affine_b[c] + dot(w[b,:], affine_w[c,:])
__global__ void k_style(const float* __restrict__ w, const float* __restrict__ aw,
                        const float* __restrict__ ab, float* __restrict__ style) {
    int idx = blockIdx.x * 4 + (threadIdx.x >> 6);
    int lane = threadIdx.x & 63;
    int b = idx >> 9, c = idx & 511;
    const float* wp = w + b * 512;
    const float* ap = aw + (size_t)c * 512;
    float s = 0.f;
    #pragma unroll
    for (int i = 0; i < 8; ++i) s += wp[lane + i * 64] * ap[lane + i * 64];
    #pragma unroll
    for (int m = 32; m; m >>= 1) s += __shfl_xor(s, m, 64);
    if (lane == 0) style[idx] = s + ab[c] + 1.0f;
}

// K2: Wf = bf16 weights in 32x32x16 MFMA A-frag order, 32-o groups.
// o = grp*32 + (lane&31), c = chunk*32 + ks*16 + (lane>>5)*8 + e
// idx = (grp*16+chunk)*9216 + tap*1024 + ks*512 + lane*8 + e
__global__ void k_wprep(const float* __restrict__ weight, ushort* __restrict__ Wf,
                        float* __restrict__ wsq) {
    int t = blockIdx.x * 256 + threadIdx.x;          // (o,c)
    int o = t >> 9, c = t & 511;
    int grp = o >> 5, mrow = o & 31;
    int chunk = c >> 5, ks = (c >> 4) & 1, khi = (c >> 3) & 1, e = c & 7;
    int lane = khi * 32 + mrow;
    size_t base = (size_t)(grp * 16 + chunk) * 9216
                + (size_t)ks * 512 + (size_t)lane * 8 + e;
    const float* wp = weight + (size_t)t * 9;
    float sq = 0.f;
    #pragma unroll
    for (int j = 0; j < 9; ++j) {
        float v = wp[j];
        sq += v * v;
        Wf[base + (size_t)j * 1024] = (ushort)bf16rne(v);
    }
    wsq[t] = sq;
}

// K3: sigma[b][o] = rsqrt( sum_c style^2[b,c] * wsq[o,c] + eps )
__global__ void k_sigma(const float* __restrict__ style, const float* __restrict__ wsq,
                        float* __restrict__ sigma) {
    int idx = blockIdx.x * 4 + (threadIdx.x >> 6);
    int lane = threadIdx.x & 63;
    int b = idx >> 9, o = idx & 511;
    const float* sp = style + b * 512;
    const float* qp = wsq + (size_t)o * 512;
    float s = 0.f;
    #pragma unroll
    for (int i = 0; i < 8; ++i) {
        float st = sp[lane + i * 64];
        s += st * st * qp[lane + i * 64];
    }
    #pragma unroll
    for (int m = 32; m; m >>= 1) s += __shfl_xor(s, m, 64);
    if (lane == 0) sigma[idx] = rsqrtf(s + 1e-8f);
}

// K_premod: xb[b][y][x][c] = bf16( x[b][c][y][x] * style[b][c] )   (NHWC)
__global__ void k_premod(const float* __restrict__ x, const float* __restrict__ style,
                         ushort* __restrict__ xb) {
    int bid = blockIdx.x;            // b*64 + y
    int b = bid >> 6, y = bid & 63;
    int xcol = threadIdx.x >> 2, cg = threadIdx.x & 3;
    const float* sp = style + b * 512;
    #pragma unroll 1
    for (int cb = 0; cb < 16; ++cb) {
        int c0 = cb * 32 + cg * 8;
        float v[8];
        #pragma unroll
        for (int j = 0; j < 8; ++j)
            v[j] = x[((size_t)(b * 512 + c0 + j) * 64 + y) * 64 + xcol] * sp[c0 + j];
        uint4 pk;
        pk.x = bf16rne(v[0]) | (bf16rne(v[1]) << 16);
        pk.y = bf16rne(v[2]) | (bf16rne(v[3]) << 16);
        pk.z = bf16rne(v[4]) | (bf16rne(v[5]) << 16);
        pk.w = bf16rne(v[6]) | (bf16rne(v[7]) << 16);
        *(uint4*)&xb[((size_t)(b * 64 + y) * 64 + xcol) * 512 + c0] = pk;
    }
}

// load A tap-row DY of chunk CC into slot array SL (6 uint4: dx*2+ks)
#define ALOAD(SL, DY, CC) { \
    const ushort* p_ = Wgrp + (size_t)(CC) * 9216 + (DY) * 3072; \
    _Pragma("unroll") for (int q_ = 0; q_ < 6; ++q_) \
        SL[q_] = *(const uint4*)(p_ + q_ * 512); }

// B fragment: input row R, tap dx DX, 32-col group CG, k-half KS
// slot-major LDS: addr = ((R*4 + KS*2 + hi)*66 + CG*32 + l31 + DX) * 16B
#define BRD(R, DX, CG, KS) \
    (*(const bf16x8*)&sX[cur][(((R) * 4 + (KS) * 2 + hi) * 66 + (CG) * 32 + l31 + (DX)) * 8])

// MFMA group: A-slot S (tap-row), output row H
#define HG(S, H) \
    _Pragma("unroll") for (int dx_ = 0; dx_ < 3; ++dx_) \
    _Pragma("unroll") for (int ks_ = 0; ks_ < 2; ++ks_) \
    _Pragma("unroll") for (int cg_ = 0; cg_ < 2; ++cg_) \
        acc[(H) * 2 + cg_] = __builtin_amdgcn_mfma_f32_32x32x16_bf16( \
            *(const bf16x8*)&S[dx_ * 2 + ks_], bv[dx_ * 4 + cg_ * 2 + ks_], \
            acc[(H) * 2 + cg_], 0, 0, 0);

#define PHASE(R, BODY) { \
    bf16x8 bv[12]; \
    _Pragma("unroll") for (int dx_ = 0; dx_ < 3; ++dx_) \
    _Pragma("unroll") for (int cg_ = 0; cg_ < 2; ++cg_) \
    _Pragma("unroll") for (int ks_ = 0; ks_ < 2; ++ks_) \
        bv[dx_ * 4 + cg_ * 2 + ks_] = BRD(R, dx_, cg_, ks_); \
    __builtin_amdgcn_s_setprio(1); \
    BODY \
    __builtin_amdgcn_s_setprio(0); }

// K4: implicit-GEMM conv, 32x32x16 MFMA. Block: 128 o x 128 px (2 rows),
// 4 waves of 32o x 128px. xb NHWC bf16 staging, slot-major LDS, 2 waves/SIMD.
__global__ __launch_bounds__(256, 2) void k_conv(
    const ushort* __restrict__ xb, const ushort* __restrict__ Wf,
    const float* __restrict__ sigma, const float* __restrict__ bias,
    float* __restrict__ out) {

    __shared__ ushort sX[2][4 * 4 * 66 * 8];   // [buf][row][slot][col][8], 33.8 KB

    const int tid = threadIdx.x, bid = blockIdx.x;
    const int pb = bid & 255, ob = bid >> 8;   // o-major outer for Wf L2 locality
    const int b = pb >> 5, y0 = (pb & 31) * 2;
    const int wv = tid >> 6, lane = tid & 63;
    const int l31 = lane & 31, hi = lane >> 5;

    // staging role: thread owns (scol, skg); stages all 4 input rows
    const int scol = tid >> 2;
    const int skg = tid & 3;
    const int colpos = scol + 1;
    const ushort* xrow_base = xb + ((size_t)(b * 64) * 64 + scol) * 512 + skg * 8;

    const int grp = ob * 4 + wv;
    const ushort* Wgrp = Wf + (size_t)grp * 147456 + lane * 8;

    f32x16 acc[4];
    #pragma unroll
    for (int j = 0; j < 4; ++j)
        acc[j] = (f32x16){0,0,0,0,0,0,0,0,0,0,0,0,0,0,0,0};

    // zero halo pads (col 0 and 65, all rows/slots, both buffers) once
    if (tid < 64) {
        int buf = tid >> 5, i = tid & 31;
        int r = i >> 3, s = (i >> 1) & 3, side = i & 1;
        *(uint4*)&sX[buf][((r * 4 + s) * 66 + side * 65) * 8] = make_uint4(0u, 0u, 0u, 0u);
    }

    uint4 xs[4];
    // prologue: stage chunk 0 into buf 0
    #pragma unroll
    for (int p = 0; p < 4; ++p) {
        int yy = y0 - 1 + p;
        xs[p] = ((unsigned)yy < 64u)
              ? *(const uint4*)(xrow_base + (size_t)yy * 32768)
              : make_uint4(0u, 0u, 0u, 0u);
    }
    #pragma unroll
    for (int p = 0; p < 4; ++p)
        *(uint4*)&sX[0][((p * 4 + skg) * 66 + colpos) * 8] = xs[p];

    uint4 a0[6], a1[6], a2[6];
    ALOAD(a0, 0, 0) ALOAD(a1, 1, 0) ALOAD(a2, 2, 0)
    __syncthreads();

    int cur = 0;
    #pragma unroll 1
    for (int cci = 0; cci < 16; ++cci) {
        const int ncc = (cci + 1) & 15;      // wrap: harmless in-bounds reload

        // T14: issue next chunk's x loads early (hide under MFMA phases)
        #pragma unroll
        for (int p = 0; p < 4; ++p) {
            int yy = y0 - 1 + p;
            xs[p] = ((unsigned)yy < 64u)
                  ? *(const uint4*)(xrow_base + (size_t)yy * 32768 + ncc * 32)
                  : make_uint4(0u, 0u, 0u, 0u);
        }

        // input-row phases; B-frag shared across both h consumers
        PHASE(0, HG(a0, 0))
        PHASE(1, HG(a1, 0) HG(a0, 1))
        ALOAD(a0, 0, ncc)                    // dy0 dead after phase 1
        PHASE(2, HG(a2, 0) HG(a1, 1))
        ALOAD(a1, 1, ncc)                    // dy1 dead after phase 2
        PHASE(3, HG(a2, 1))

        // commit next chunk's x tile, single barrier
        #pragma unroll
        for (int p = 0; p < 4; ++p)
            *(uint4*)&sX[cur ^ 1][((p * 4 + skg) * 66 + colpos) * 8] = xs[p];
        __syncthreads();
        cur ^= 1;
        ALOAD(a2, 2, ncc)                    // dy2 first used 2 phases into next chunk
    }

    // epilogue: out = acc * sigma + bias.  C/D: col=lane&31, row=(reg&3)+8*(reg>>2)+4*hi
    const float* sigb = sigma + b * 512;
    #pragma unroll
    for (int h = 0; h < 2; ++h) {
        #pragma unroll
        for (int cg = 0; cg < 2; ++cg) {
            #pragma unroll
            for (int reg = 0; reg < 16; ++reg) {
                int row = (reg & 3) + 8 * (reg >> 2) + 4 * hi;
                int o = grp * 32 + row;
                float v = acc[h * 2 + cg][reg] * sigb[o] + bias[o];
                out[(((size_t)(b * 512 + o) * 64) + y0 + h) * 64 + cg * 32 + l31] = v;
            }
        }
    }
}

extern "C" void kernel_launch(void* const* d_in, const int* in_sizes, int n_in,
                              void* d_out, int out_size, void* d_ws, size_t ws_size,
                              hipStream_t stream) {
    const float* x    = (const float*)d_in[0];
    const float* w    = (const float*)d_in[1];
    const float* wt   = (const float*)d_in[2];
    const float* bias = (const float*)d_in[3];
    const float* aw   = (const float*)d_in[4];
    const float* ab   = (const float*)d_in[5];
    float* out = (float*)d_out;

    // ws layout: style(16KB) | sigma(16KB) | wsq(1MB) | Wf(4.5MB) | xb(32MB)
    float* style  = (float*)d_ws;
    float* sigmap = style + 4096;
    float* wsq    = sigmap + 4096;
    ushort* Wf    = (ushort*)(wsq + 512 * 512);
    ushort* xbm   = Wf + 2359296;

    k_style <<<1024, 256, 0, stream>>>(w, aw, ab, style);
    k_wprep <<<1024, 256, 0, stream>>>(wt, Wf, wsq);
    k_premod<<< 512, 256, 0, stream>>>(x, style, xbm);
    k_sigma <<<1024, 256, 0, stream>>>(style, wsq, sigmap);
    k_conv  <<<1024, 256, 0, stream>>>(xbm, Wf, sigmap, bias, out);
}

// Round 6
// 160.510 us; speedup vs baseline: 1.2087x; 1.2087x over previous
//
#include <hip/hip_runtime.h>
#include <hip/hip_bf16.h>

typedef __attribute__((ext_vector_type(8))) short bf16x8;
typedef __attribute__((ext_vector_type(4))) float f32x4;

#define FSW(c) (((c) >> 1) & 3)

static __device__ __forceinline__ uint bf16rne(float f) {
    uint u = __float_as_uint(f);
    return (u + 0x7fffu + ((u >> 16) & 1u)) >> 16;
}

// K1: style_plus1[b][c] = 1 + affine_b[c] + dot(w[b,:], affine_w[c,:])
__global__ void k_style(const float* __restrict__ w, const float* __restrict__ aw,
                        const float* __restrict__ ab, float* __restrict__ style) {
    int idx = blockIdx.x * 4 + (threadIdx.x >> 6);
    int lane = threadIdx.x & 63;
    int b = idx >> 9, c = idx & 511;
    const float* wp = w + b * 512;
    const float* ap = aw + (size_t)c * 512;
    float s = 0.f;
    #pragma unroll
    for (int i = 0; i < 8; ++i) s += wp[lane + i * 64] * ap[lane + i * 64];
    #pragma unroll
    for (int m = 32; m; m >>= 1) s += __shfl_xor(s, m, 64);
    if (lane == 0) style[idx] = s + ab[c] + 1.0f;
}

// K2: Wf[grp16][chunk16][tap9][fm2][lane64][8] = bf16 weight in 16x16x32 MFMA
// A-frag order; wsq[o][c] = sum_tap w^2
__global__ void k_wprep(const float* __restrict__ weight, ushort* __restrict__ Wf,
                        float* __restrict__ wsq) {
    int t = blockIdx.x * 256 + threadIdx.x;          // (o,c)
    int o = t >> 9, c = t & 511;
    int grp = o >> 5, rr = o & 31, fm = rr >> 4, l15r = rr & 15;
    int chunkid = c >> 5, kgw = (c >> 3) & 3, kk = c & 7;
    int lanew = kgw * 16 + l15r;
    const float* wp = weight + (size_t)t * 9;
    size_t G = (size_t)(grp * 16 + chunkid);
    size_t base = G * 9216 + (size_t)fm * 512 + (size_t)lanew * 8 + kk;
    float sq = 0.f;
    #pragma unroll
    for (int j = 0; j < 9; ++j) {
        float v = wp[j];
        sq += v * v;
        Wf[base + (size_t)j * 1024] = (ushort)bf16rne(v);
    }
    wsq[t] = sq;
}

// K3: sigma[b][o] = rsqrt( sum_c style^2[b,c] * wsq[o,c] + eps )
__global__ void k_sigma(const float* __restrict__ style, const float* __restrict__ wsq,
                        float* __restrict__ sigma) {
    int idx = blockIdx.x * 4 + (threadIdx.x >> 6);
    int lane = threadIdx.x & 63;
    int b = idx >> 9, o = idx & 511;
    const float* sp = style + b * 512;
    const float* qp = wsq + (size_t)o * 512;
    float s = 0.f;
    #pragma unroll
    for (int i = 0; i < 8; ++i) {
        float st = sp[lane + i * 64];
        s += st * st * qp[lane + i * 64];
    }
    #pragma unroll
    for (int m = 32; m; m >>= 1) s += __shfl_xor(s, m, 64);
    if (lane == 0) sigma[idx] = rsqrtf(s + 1e-8f);
}

// K_premod: xb[b][y][x][c] = bf16( x[b][c][y][x] * style[b][c] )   (NHWC)
__global__ void k_premod(const float* __restrict__ x, const float* __restrict__ style,
                         ushort* __restrict__ xb) {
    int bid = blockIdx.x;            // b*64 + y
    int b = bid >> 6, y = bid & 63;
    int xcol = threadIdx.x >> 2, cg = threadIdx.x & 3;
    const float* sp = style + b * 512;
    #pragma unroll 1
    for (int cb = 0; cb < 16; ++cb) {
        int c0 = cb * 32 + cg * 8;
        float v[8];
        #pragma unroll
        for (int j = 0; j < 8; ++j)
            v[j] = x[((size_t)(b * 512 + c0 + j) * 64 + y) * 64 + xcol] * sp[c0 + j];
        uint4 pk;
        pk.x = bf16rne(v[0]) | (bf16rne(v[1]) << 16);
        pk.y = bf16rne(v[2]) | (bf16rne(v[3]) << 16);
        pk.z = bf16rne(v[4]) | (bf16rne(v[5]) << 16);
        pk.w = bf16rne(v[6]) | (bf16rne(v[7]) << 16);
        *(uint4*)&xb[((size_t)(b * 64 + y) * 64 + xcol) * 512 + c0] = pk;
    }
}

// JIT A-frag load: tap-row DY of chunk CC into SL (6 uint4: dx*2+fm)
#define ALOADJ(SL, DY, CC) { \
    const ushort* p_ = Wbase + (size_t)(CC) * 9216 + (DY) * 3072; \
    _Pragma("unroll") for (int q_ = 0; q_ < 6; ++q_) \
        SL[q_] = *(const uint4*)(p_ + q_ * 512); }

// B-frag row load into ping-pong buffer BV (12 reads)
#define LOADBV(BV, R) \
    _Pragma("unroll") for (int dx_ = 0; dx_ < 3; ++dx_) \
    _Pragma("unroll") for (int q_ = 0; q_ < 4; ++q_) { \
        int ci_ = dx_ + q_ * 16 + l15; \
        BV[dx_ * 4 + q_] = *(const bf16x8*)&sX[cur][((R) * 66 + ci_) * 32 + ((kg ^ FSW(ci_)) * 8)]; \
    }

#define MM(AV, BV, FM, FN) \
    acc[FM][FN] = __builtin_amdgcn_mfma_f32_16x16x32_bf16( \
        *(const bf16x8*)&(AV), (BV), acc[FM][FN], 0, 0, 0)

#define HGROUP(AARR, BV, H) \
    _Pragma("unroll") for (int dx_ = 0; dx_ < 3; ++dx_) { \
      _Pragma("unroll") for (int q_ = 0; q_ < 4; ++q_) { \
        MM(AARR[dx_ * 2 + 0], BV[dx_ * 4 + q_], 0, (H) * 4 + q_); \
        MM(AARR[dx_ * 2 + 1], BV[dx_ * 4 + q_], 1, (H) * 4 + q_); \
      } }

// K4: implicit-GEMM conv, 16x16x32 MFMA. Block: 128 o x 128 px (2 rows),
// 4 waves of 32o x 128px. bv register double-buffer (phase-ahead ds_reads),
// JIT A ping-pong from L2, setprio around MFMA clusters, 1 barrier/chunk.
__global__ __launch_bounds__(256, 2) void k_conv(
    const ushort* __restrict__ xb, const ushort* __restrict__ Wf,
    const float* __restrict__ sigma, const float* __restrict__ bias,
    float* __restrict__ out) {

    __shared__ ushort sX[2][4 * 66 * 32];   // [buf][row][col][32ch], swizzled 16B slots

    const int tid = threadIdx.x, bid = blockIdx.x;
    const int ob = bid & 3, pb = bid >> 2;
    const int b = pb >> 5, y0 = (pb & 31) * 2;
    const int o0 = ob * 128;
    const int wv = tid >> 6, lane = tid & 63;
    const int l15 = lane & 15, kg = lane >> 4;

    // x staging role: thread owns (scol, skg); stages all 4 input rows
    const int scol = (tid >> 2) & 63;
    const int skg = tid & 3;
    const int colpos = scol + 1;
    const int sslot = (skg ^ FSW(colpos)) * 8;
    const ushort* xrow_base = xb + ((size_t)(b * 64) * 64 + scol) * 512 + skg * 8;

    const int grp = ob * 4 + wv;
    const ushort* Wbase = Wf + (size_t)grp * 147456 + lane * 8;

    f32x4 acc[2][8];
    #pragma unroll
    for (int i = 0; i < 2; ++i)
        #pragma unroll
        for (int j = 0; j < 8; ++j) acc[i][j] = (f32x4){0.f, 0.f, 0.f, 0.f};

    // zero halo pads (colpos 0 and 65, both buffers) once
    if (tid < 64) {
        int buf = tid >> 5, rem = tid & 31;
        int r = rem >> 3, side = (rem >> 2) & 1, sl = rem & 3;
        int cp = side * 65;
        *(uint4*)&sX[buf][(r * 66 + cp) * 32 + sl * 8] = make_uint4(0u, 0u, 0u, 0u);
    }

    uint4 xs[4];
    // prologue: stage chunk 0 into buf 0
    #pragma unroll
    for (int p = 0; p < 4; ++p) {
        int yy = y0 - 1 + p;
        xs[p] = ((unsigned)yy < 64u)
              ? *(const uint4*)(xrow_base + (size_t)yy * 32768)
              : make_uint4(0u, 0u, 0u, 0u);
    }
    #pragma unroll
    for (int p = 0; p < 4; ++p)
        *(uint4*)&sX[0][(p * 66 + colpos) * 32 + sslot] = xs[p];
    __syncthreads();

    int cur = 0;
    bf16x8 bvA[12], bvB[12];
    uint4 aA[6], aB[6];

    #pragma unroll 1
    for (int cci = 0; cci < 16; ++cci) {
        const int ncc = (cci + 1) & 15;   // wrap: harmless in-bounds reload

        // T14: issue next chunk's x global loads first (longest latency)
        #pragma unroll
        for (int p = 0; p < 4; ++p) {
            int yy = y0 - 1 + p;
            xs[p] = ((unsigned)yy < 64u)
                  ? *(const uint4*)(xrow_base + (size_t)yy * 32768 + ncc * 32)
                  : make_uint4(0u, 0u, 0u, 0u);
        }

        // chunk head: row0 B-frags + dy0 A-frags
        LOADBV(bvA, 0)
        ALOADJ(aA, 0, cci)

        // p0: prefetch row1/dy1, compute row0
        LOADBV(bvB, 1)
        ALOADJ(aB, 1, cci)
        __builtin_amdgcn_s_setprio(1);
        HGROUP(aA, bvA, 0)
        __builtin_amdgcn_s_setprio(0);

        // p1: prefetch row2, compute row1 (dy0->h1 via aA, dy1->h0 via aB)
        LOADBV(bvA, 2)
        __builtin_amdgcn_s_setprio(1);
        HGROUP(aA, bvB, 1)
        HGROUP(aB, bvB, 0)
        __builtin_amdgcn_s_setprio(0);
        ALOADJ(aA, 2, cci)                // aA free -> dy2 of this chunk

        // p2: prefetch row3, compute row2 (dy1->h1 via aB, dy2->h0 via aA)
        LOADBV(bvB, 3)
        __builtin_amdgcn_s_setprio(1);
        HGROUP(aB, bvA, 1)
        HGROUP(aA, bvA, 0)
        __builtin_amdgcn_s_setprio(0);

        // p3: compute row3 (dy2->h1 via aA)
        __builtin_amdgcn_s_setprio(1);
        HGROUP(aA, bvB, 1)
        __builtin_amdgcn_s_setprio(0);

        // commit next chunk's x tile, single barrier
        #pragma unroll
        for (int p = 0; p < 4; ++p)
            *(uint4*)&sX[cur ^ 1][(p * 66 + colpos) * 32 + sslot] = xs[p];
        __syncthreads();
        cur ^= 1;
    }

    // epilogue: out = acc * sigma + bias
    const float* sigb = sigma + b * 512;
    #pragma unroll
    for (int fm = 0; fm < 2; ++fm) {
        #pragma unroll
        for (int j = 0; j < 4; ++j) {
            int o = o0 + wv * 32 + fm * 16 + kg * 4 + j;
            float sg = sigb[o];
            float bs = bias[o];
            float* op = out + ((size_t)(b * 512 + o) * 64 + y0) * 64;
            #pragma unroll
            for (int fn = 0; fn < 8; ++fn)
                op[(fn >> 2) * 64 + (fn & 3) * 16 + l15] = acc[fm][fn][j] * sg + bs;
        }
    }
}

extern "C" void kernel_launch(void* const* d_in, const int* in_sizes, int n_in,
                              void* d_out, int out_size, void* d_ws, size_t ws_size,
                              hipStream_t stream) {
    const float* x    = (const float*)d_in[0];
    const float* w    = (const float*)d_in[1];
    const float* wt   = (const float*)d_in[2];
    const float* bias = (const float*)d_in[3];
    const float* aw   = (const float*)d_in[4];
    const float* ab   = (const float*)d_in[5];
    float* out = (float*)d_out;

    // ws layout: style(16KB) | sigma(16KB) | wsq(1MB) | Wf(4.5MB) | xb(32MB)
    float* style  = (float*)d_ws;
    float* sigmap = style + 4096;
    float* wsq    = sigmap + 4096;
    ushort* Wf    = (ushort*)(wsq + 512 * 512);
    ushort* xbm   = Wf + 2359296;

    k_style <<<1024, 256, 0, stream>>>(w, aw, ab, style);
    k_wprep <<<1024, 256, 0, stream>>>(wt, Wf, wsq);
    k_premod<<< 512, 256, 0, stream>>>(x, style, xbm);
    k_sigma <<<1024, 256, 0, stream>>>(style, wsq, sigmap);
    k_conv  <<<1024, 256, 0, stream>>>(xbm, Wf, sigmap, bias, out);
}